// Round 15
// baseline (90.928 us; speedup 1.0000x reference)
//
#include <hip/hip_runtime.h>
#include <hip/hip_bf16.h>

typedef unsigned short u16;
typedef unsigned int u32;
typedef __attribute__((ext_vector_type(8))) short bf16x8;
typedef __attribute__((ext_vector_type(4))) float f32x4;
typedef __attribute__((ext_vector_type(4))) int i32x4;

#define N_HEADS 9
#define T_SEQ 2048
#define BATCH 4
#define CDIM 576
#define ROWS (BATCH * T_SEQ) /* 8192 */
#define NBH (BATCH * N_HEADS) /* 36 */
#define PART_SLOT ((size_t)NBH * T_SEQ * 32) /* u16 elements per partial slot */

__device__ __forceinline__ u16 f2bf(float f) {
    u32 u = __float_as_uint(f);
    u32 r = u + 0x7FFFu + ((u >> 16) & 1u);
    return (u16)(r >> 16);
}
__device__ __forceinline__ float bf2f(u16 u) { return __uint_as_float(((u32)u) << 16); }
__device__ __forceinline__ u32 cvt_pk_bf16(float lo, float hi) {
    u32 r;
    asm("v_cvt_pk_bf16_f32 %0, %1, %2" : "=v"(r) : "v"(lo), "v"(hi));
    return r;
}
__device__ __forceinline__ float exp2_raw(float x) {
    float r;
    asm("v_exp_f32 %0, %1" : "=v"(r) : "v"(x));
    return r;
}

// ---------------- merged prep: weights + trig tables ----------------
__global__ __launch_bounds__(256) void prep_wt(const float* __restrict__ Wq, const float* __restrict__ Wk,
                                               const float* __restrict__ Wv, const float* __restrict__ Wo,
                                               u16* __restrict__ WcT, u16* __restrict__ WoSubT,
                                               float* __restrict__ cosT, float* __restrict__ sinT) {
    int idx = blockIdx.x * 256 + threadIdx.x;
    if (idx < 576 * 576) {
        int n = idx / 576, k = idx - n * 576;
        float v;
        if (n < 189)      v = Wq[(size_t)k * 576 + (n / 21) * 64 + (n % 21)];
        else if (n < 378) v = Wk[(size_t)k * 189 + (n - 189)];
        else if (n < 567) v = Wv[(size_t)k * 189 + (n - 378)];
        else              v = 0.f;
        WcT[(size_t)n * 576 + k] = f2bf(v);
    }
    if (idx < 576 * 192) {
        int n = idx / 192, k = idx - n * 192;
        float v = 0.f;
        if (k < 189) v = Wo[(size_t)((k / 21) * 64 + (k % 21)) * 576 + n];
        WoSubT[(size_t)n * 192 + k] = f2bf(v);
    }
    if (idx < T_SEQ * 21) {
        int t = idx / 21, d = idx - t * 21;
        int i = (d < 11) ? d : d - 11;
        float e = (2.0f * (float)i) / 21.0f;
        float invf = exp2f(-e * 13.287712379549449f); // 10000^-e
        float ang = (float)t * invf;
        cosT[idx] = cosf(ang);
        sinT[idx] = sinf(ang);
    }
}

// ---------------- bf16 MFMA GEMM, BK=64: C[M,N] = A[M,K] * BT[N,K]^T ----------------
// 128x64 tile, 4 waves, 64-deep k-step (16 MFMA/wave between barrier pairs).
// 1-D grid, m = bx&63, n = bx>>6: blocks sharing an A panel land on the same XCD L2.
// AF32: A f32, converted in staging. XOR chunk swizzle: chunk c of row r stored at c^(r&7).

template <int AF32, int OUTF32>
__global__ __launch_bounds__(256) void gemm_mfma(const void* __restrict__ Av, const u16* __restrict__ BT,
                                                 void* __restrict__ Cout, int K, int lda, int ldbt, int ldc) {
    __shared__ u16 As[128][64];
    __shared__ u16 Bs[64][64];
    const int tid = threadIdx.x;
    const int lane = tid & 63, w = tid >> 6;
    const int m0 = (blockIdx.x & 63) * 128, n0 = (blockIdx.x >> 6) * 64;
    const int k15 = lane & 15, g = lane >> 4;

    const int arow = tid >> 1;          // 0..127, 2 threads/row
    const int ac0 = (tid & 1) * 4;      // chunks ac0..ac0+3
    const int brow = tid >> 2;          // 0..63, 4 threads/row
    const int bc0 = (tid & 3) * 2;      // chunks bc0, bc0+1

    f32x4 zero = {0.f, 0.f, 0.f, 0.f};
    f32x4 acc[2][4];
#pragma unroll
    for (int hf = 0; hf < 2; hf++)
#pragma unroll
        for (int n = 0; n < 4; n++) acc[hf][n] = zero;

    const float* Af = (const float*)Av;
    const u16*   Ab = (const u16*)Av;

    float4 af[8];
    i32x4 av[4];
    i32x4 bv[2];
    if (AF32) {
        const float* ap = &Af[(size_t)(m0 + arow) * lda + ac0 * 8];
#pragma unroll
        for (int j = 0; j < 8; j++) af[j] = *(const float4*)&ap[j * 4];
    } else {
#pragma unroll
        for (int j = 0; j < 4; j++)
            av[j] = *(const i32x4*)&Ab[(size_t)(m0 + arow) * lda + (ac0 + j) * 8];
    }
#pragma unroll
    for (int j = 0; j < 2; j++)
        bv[j] = *(const i32x4*)&BT[(size_t)(n0 + brow) * ldbt + (bc0 + j) * 8];

    for (int k0 = 0; k0 < K; k0 += 64) {
        __syncthreads();
        if (AF32) {
#pragma unroll
            for (int j = 0; j < 4; j++) {
                i32x4 wv;
                wv[0] = (int)cvt_pk_bf16(af[2*j].x, af[2*j].y);
                wv[1] = (int)cvt_pk_bf16(af[2*j].z, af[2*j].w);
                wv[2] = (int)cvt_pk_bf16(af[2*j+1].x, af[2*j+1].y);
                wv[3] = (int)cvt_pk_bf16(af[2*j+1].z, af[2*j+1].w);
                *(i32x4*)&As[arow][((ac0 + j) ^ (arow & 7)) * 8] = wv;
            }
        } else {
#pragma unroll
            for (int j = 0; j < 4; j++)
                *(i32x4*)&As[arow][((ac0 + j) ^ (arow & 7)) * 8] = av[j];
        }
#pragma unroll
        for (int j = 0; j < 2; j++)
            *(i32x4*)&Bs[brow][((bc0 + j) ^ (brow & 7)) * 8] = bv[j];
        __syncthreads();
        int k1 = k0 + 64;
        if (k1 < K) {
            if (AF32) {
                const float* ap = &Af[(size_t)(m0 + arow) * lda + k1 + ac0 * 8];
#pragma unroll
                for (int j = 0; j < 8; j++) af[j] = *(const float4*)&ap[j * 4];
            } else {
#pragma unroll
                for (int j = 0; j < 4; j++)
                    av[j] = *(const i32x4*)&Ab[(size_t)(m0 + arow) * lda + k1 + (ac0 + j) * 8];
            }
#pragma unroll
            for (int j = 0; j < 2; j++)
                bv[j] = *(const i32x4*)&BT[(size_t)(n0 + brow) * ldbt + k1 + (bc0 + j) * 8];
        }
        const int ar0 = w * 32 + k15;
        const int asw = ar0 & 7;  // (ar0+16)&7 == ar0&7
#pragma unroll
        for (int kk = 0; kk < 2; kk++) {
            bf16x8 a0 = *(const bf16x8*)&As[ar0][((kk * 4 + g) ^ asw) * 8];
            bf16x8 a1 = *(const bf16x8*)&As[ar0 + 16][((kk * 4 + g) ^ asw) * 8];
#pragma unroll
            for (int n = 0; n < 4; n++) {
                int br = n * 16 + k15;
                bf16x8 b = *(const bf16x8*)&Bs[br][((kk * 4 + g) ^ (br & 7)) * 8];
                acc[0][n] = __builtin_amdgcn_mfma_f32_16x16x32_bf16(a0, b, acc[0][n], 0, 0, 0);
                acc[1][n] = __builtin_amdgcn_mfma_f32_16x16x32_bf16(a1, b, acc[1][n], 0, 0, 0);
            }
        }
    }
#pragma unroll
    for (int hf = 0; hf < 2; hf++)
#pragma unroll
        for (int n = 0; n < 4; n++)
#pragma unroll
            for (int i = 0; i < 4; i++) {
                int row = m0 + w * 32 + hf * 16 + g * 4 + i;
                int col = n0 + n * 16 + k15;
                float v = acc[hf][n][i];
                if (OUTF32) ((float*)Cout)[(size_t)row * ldc + col] = v;
                else        ((u16*)Cout)[(size_t)row * ldc + col] = f2bf(v);
            }
}

// ---------------- merged repack: rope Q/K + V transpose, vectorized loads ----------------

__global__ __launch_bounds__(256) void repack_qkv(const u16* __restrict__ qkv,
                                                  const float* __restrict__ cosT,
                                                  const float* __restrict__ sinT,
                                                  u16* __restrict__ Qp, u16* __restrict__ Kp,
                                                  u16* __restrict__ Vp) {
    __shared__ u16 Qs[64][40];
    __shared__ u16 Ksh[64][40];
    __shared__ u16 Vsh[64][40];
    const int tid = threadIdx.x;
    const int bh = blockIdx.y;
    const int b = bh / N_HEADS, h = bh - b * N_HEADS;
    const int t0 = blockIdx.x * 64;

    const int qa = (h * 21) & ~7,        qoff = h * 21 - qa;
    const int ka = (189 + h * 21) & ~7,  koff = 189 + h * 21 - ka;
    const int va = (378 + h * 21) & ~7,  voff = 378 + h * 21 - va;

#pragma unroll
    for (int it = 0; it < 3; ++it) {
        int idx = tid + it * 256;  // 0..767
        int row = idx / 12;
        int r12 = idx - row * 12;
        int stream = r12 >> 2, chunk = r12 & 3;
        int off = (stream == 0) ? qa : (stream == 1) ? ka : va;
        const u16* src = qkv + (size_t)(b * T_SEQ + t0 + row) * CDIM + off + chunk * 8;
        i32x4 v = *(const i32x4*)src;
        u16* dst = (stream == 0) ? &Qs[row][0] : (stream == 1) ? &Ksh[row][0] : &Vsh[row][0];
        *(i32x4*)&dst[chunk * 8] = v;
    }
    __syncthreads();

    const int r = tid >> 2, c = tid & 3;
    const int t = t0 + r;
    const float* cr = cosT + t * 21;
    const float* sr = sinT + t * 21;
    u32 wq[4] = {0, 0, 0, 0}, wk[4] = {0, 0, 0, 0};
    const float sc = 0.18033688011112042f; // 0.125 * log2(e)
#pragma unroll
    for (int j = 0; j < 8; j++) {
        int d = c * 8 + j;
        float vq = 0.f, vk = 0.f;
        if (d < 21) {
            int pd = (d < 11) ? d + 10 : d - 11;
            float cc = cr[d], ss = sr[d];
            float qv = bf2f(Qs[r][qoff + d]),  qp = bf2f(Qs[r][qoff + pd]);
            float kv = bf2f(Ksh[r][koff + d]), kp = bf2f(Ksh[r][koff + pd]);
            float rq = (d < 11) ? -qp : qp;
            float rk = (d < 11) ? -kp : kp;
            vq = (qv * cc + rq * ss) * sc;
            vk = kv * cc + rk * ss;
        }
        wq[j >> 1] |= (u32)f2bf(vq) << ((j & 1) * 16);
        wk[j >> 1] |= (u32)f2bf(vk) << ((j & 1) * 16);
    }
    size_t obase = ((size_t)bh * T_SEQ + t) * 32 + c * 8;
    i32x4 q4; q4[0] = (int)wq[0]; q4[1] = (int)wq[1]; q4[2] = (int)wq[2]; q4[3] = (int)wq[3];
    i32x4 k4; k4[0] = (int)wk[0]; k4[1] = (int)wk[1]; k4[2] = (int)wk[2]; k4[3] = (int)wk[3];
    *(i32x4*)&Qp[obase] = q4;
    *(i32x4*)&Kp[obase] = k4;

    const int dv = tid >> 3, tc = tid & 7;
    u32 wv[4];
#pragma unroll
    for (int j = 0; j < 4; j++) {
        u16 lo, hi;
        if (dv < 21)      { lo = Vsh[tc * 8 + j * 2][voff + dv]; hi = Vsh[tc * 8 + j * 2 + 1][voff + dv]; }
        else if (dv == 31){ lo = 0x3F80; hi = 0x3F80; }
        else              { lo = 0; hi = 0; }
        wv[j] = (u32)lo | ((u32)hi << 16);
    }
    i32x4 v4; v4[0] = (int)wv[0]; v4[1] = (int)wv[1]; v4[2] = (int)wv[2]; v4[3] = (int)wv[3];
    *(i32x4*)&Vp[((size_t)bh * 32 + dv) * T_SEQ + t0 + tc * 8] = v4;
}

// ---------------- split-K MFMA flash attention: 128 q/block, 8 waves, 256-key units ----------------
// Fixed-base softmax (bounded scores) => linear in keys => split-K partials.
// One staged 256-key unit feeds 8 waves => barrier pairs per score halved again vs r14.
// Inner loop = 2 passes of the double-Pt 2-sub pipeline. Wave w's diagonal 64-key tile:
// kd = 2*qt2 + (w>>2); guards kt <= kd. nc = (qt2>>2)+1 chunks (<=4 slots).

__global__ __launch_bounds__(512) void attn_mfma(const u16* __restrict__ Qp,
                                                 const u16* __restrict__ Kp,
                                                 const u16* __restrict__ Vp,
                                                 u16* __restrict__ Ybuf,
                                                 u16* __restrict__ Part) {
    __shared__ u16 Ks[256][40];       // 80B rows
    __shared__ u16 Vt[32][264];       // 528B rows
    __shared__ u16 Pt[2][8][16][72];  // [sub][wave][q][key]
    const int tid = threadIdx.x;
    const int lane = tid & 63, w = tid >> 6;   // w 0..7
    const int bh = blockIdx.y;
    const int b = bh / N_HEADS, h = bh - b * N_HEADS;
    const int k15 = lane & 15, g = lane >> 4;

    // bx -> (qt2, ci), heavy q-tiles first. nc(qt2) = (qt2>>2)+1, sum = 40.
    int qt2 = 15, ci = blockIdx.x;
    for (int q = 15; q >= 0; --q) {
        int n = (q >> 2) + 1;
        if (ci < n) { qt2 = q; break; }
        ci -= n;
    }
    const int q0 = qt2 * 128;
    const int n256 = (qt2 + 2) >> 1;     // 256-key units covering keys 0..q0+127
    const int nc = (qt2 >> 2) + 1;
    const int u_begin = (ci * n256) / nc;
    const int u_end = ((ci + 1) * n256) / nc;

    // staging: threads 0..255 stage K (256x32), 256..511 stage V (32x256); 4x16B each
    const bool isK = (tid < 256);
    const int krow = (tid & 255) >> 2, kc = tid & 3;   // K: rows krow + 64j, chunk kc
    const int vrow = (tid & 255) >> 3, vc = tid & 7;   // V: row vrow, chunks vc + 8j
    const u16* Kg = Kp + (size_t)bh * 65536 + krow * 32 + kc * 8;
    const u16* Vg = Vp + (size_t)bh * 65536 + vrow * 2048 + vc * 8;

    // Q B-fragment held in regs: B[n=q][k=d]
    bf16x8 qf = *(const bf16x8*)&Qp[(((size_t)bh << 11) + q0 + w * 16 + k15) * 32 + g * 8];

    f32x4 y0 = {0.f, 0.f, 0.f, 0.f}, y1 = {0.f, 0.f, 0.f, 0.f};
    const int qloc = (w & 3) * 16 + k15;       // q position within its 64-aligned block
    const int kd = 2 * qt2 + (w >> 2);         // wave's diagonal 64-key tile index

    // prologue loads (unit u_begin)
    u32 koff = (u32)u_begin * 8192u;           // K: u16 elems per 256-key unit (256*32)
    u32 voffu = (u32)u_begin * 256u;           // V: u16 elems per unit per d-row
    i32x4 r0, r1, r2, r3;
    if (isK) {
        r0 = *(const i32x4*)&Kg[koff];        r1 = *(const i32x4*)&Kg[koff + 2048];
        r2 = *(const i32x4*)&Kg[koff + 4096]; r3 = *(const i32x4*)&Kg[koff + 6144];
    } else {
        r0 = *(const i32x4*)&Vg[voffu];       r1 = *(const i32x4*)&Vg[voffu + 64];
        r2 = *(const i32x4*)&Vg[voffu + 128]; r3 = *(const i32x4*)&Vg[voffu + 192];
    }

    for (int u = u_begin; u < u_end; ++u) {
        __syncthreads();                       // prior compute done with LDS
        if (isK) {
            *(i32x4*)&Ks[krow][kc * 8]       = r0;
            *(i32x4*)&Ks[krow + 64][kc * 8]  = r1;
            *(i32x4*)&Ks[krow + 128][kc * 8] = r2;
            *(i32x4*)&Ks[krow + 192][kc * 8] = r3;
        } else {
            *(i32x4*)&Vt[vrow][vc * 8]       = r0;
            *(i32x4*)&Vt[vrow][vc * 8 + 64]  = r1;
            *(i32x4*)&Vt[vrow][vc * 8 + 128] = r2;
            *(i32x4*)&Vt[vrow][vc * 8 + 192] = r3;
        }
        if (u + 1 < u_end) {                   // prefetch next unit (overlaps compute)
            koff += 8192u; voffu += 256u;
            if (isK) {
                r0 = *(const i32x4*)&Kg[koff];        r1 = *(const i32x4*)&Kg[koff + 2048];
                r2 = *(const i32x4*)&Kg[koff + 4096]; r3 = *(const i32x4*)&Kg[koff + 6144];
            } else {
                r0 = *(const i32x4*)&Vg[voffu];       r1 = *(const i32x4*)&Vg[voffu + 64];
                r2 = *(const i32x4*)&Vg[voffu + 128]; r3 = *(const i32x4*)&Vg[voffu + 192];
            }
        }
        __syncthreads();                       // LDS ready

#pragma unroll
        for (int half = 0; half < 2; ++half) {
            const int ktA = u * 4 + half * 2;
            const bool do0 = (ktA <= kd);
            const bool do1 = (ktA + 1 <= kd);
            if (!do0) break;                   // wave-local skip (no sync inside)
            const int kbase = half * 128;      // Ks row / Vt col base for this half

            f32x4 s0[4], s1[4];
#pragma unroll
            for (int f = 0; f < 4; f++) {
                bf16x8 kf = *(const bf16x8*)&Ks[kbase + f * 16 + k15][g * 8];
                f32x4 z = {0.f, 0.f, 0.f, 0.f};
                s0[f] = __builtin_amdgcn_mfma_f32_16x16x32_bf16(kf, qf, z, 0, 0, 0);
            }
            if (do1) {
#pragma unroll
                for (int f = 0; f < 4; f++) {
                    bf16x8 kf = *(const bf16x8*)&Ks[kbase + 64 + f * 16 + k15][g * 8];
                    f32x4 z = {0.f, 0.f, 0.f, 0.f};
                    s1[f] = __builtin_amdgcn_mfma_f32_16x16x32_bf16(kf, qf, z, 0, 0, 0);
                }
            }
            if (ktA == kd) {
#pragma unroll
                for (int f = 0; f < 4; f++)
#pragma unroll
                    for (int i = 0; i < 4; i++)
                        if (f * 16 + g * 4 + i > qloc) s0[f][i] = -16384.f;
            }
            if (do1 && ktA + 1 == kd) {
#pragma unroll
                for (int f = 0; f < 4; f++)
#pragma unroll
                    for (int i = 0; i < 4; i++)
                        if (f * 16 + g * 4 + i > qloc) s1[f][i] = -16384.f;
            }

#pragma unroll
            for (int f = 0; f < 4; f++) {
                u32 lo = cvt_pk_bf16(exp2_raw(s0[f][0]), exp2_raw(s0[f][1]));
                u32 hi = cvt_pk_bf16(exp2_raw(s0[f][2]), exp2_raw(s0[f][3]));
                uint2 pk; pk.x = lo; pk.y = hi;
                *(uint2*)&Pt[0][w][k15][f * 16 + g * 4] = pk;
            }
            if (do1) {
#pragma unroll
                for (int f = 0; f < 4; f++) {
                    u32 lo = cvt_pk_bf16(exp2_raw(s1[f][0]), exp2_raw(s1[f][1]));
                    u32 hi = cvt_pk_bf16(exp2_raw(s1[f][2]), exp2_raw(s1[f][3]));
                    uint2 pk; pk.x = lo; pk.y = hi;
                    *(uint2*)&Pt[1][w][k15][f * 16 + g * 4] = pk;
                }
            }
            asm volatile("" ::: "memory"); // Pt writes ordered before reads (wave-local)

#pragma unroll
            for (int kh = 0; kh < 2; kh++) {
                bf16x8 pa = *(const bf16x8*)&Pt[0][w][k15][kh * 32 + g * 8];
                bf16x8 v0 = *(const bf16x8*)&Vt[k15][kbase + kh * 32 + g * 8];
                bf16x8 v1 = *(const bf16x8*)&Vt[16 + k15][kbase + kh * 32 + g * 8];
                y0 = __builtin_amdgcn_mfma_f32_16x16x32_bf16(pa, v0, y0, 0, 0, 0);
                y1 = __builtin_amdgcn_mfma_f32_16x16x32_bf16(pa, v1, y1, 0, 0, 0);
            }
            if (do1) {
#pragma unroll
                for (int kh = 0; kh < 2; kh++) {
                    bf16x8 pa = *(const bf16x8*)&Pt[1][w][k15][kh * 32 + g * 8];
                    bf16x8 v0 = *(const bf16x8*)&Vt[k15][kbase + 64 + kh * 32 + g * 8];
                    bf16x8 v1 = *(const bf16x8*)&Vt[16 + k15][kbase + 64 + kh * 32 + g * 8];
                    y0 = __builtin_amdgcn_mfma_f32_16x16x32_bf16(pa, v0, y0, 0, 0, 0);
                    y1 = __builtin_amdgcn_mfma_f32_16x16x32_bf16(pa, v1, y1, 0, 0, 0);
                }
            }
            asm volatile("" ::: "memory"); // Pt reads done before next writes
        }
    }

    if (nc == 1) { // qt2 < 4: single chunk, normalize by l (= y1 col 15 ones-column), write
#pragma unroll
        for (int i = 0; i < 4; i++) {
            float li = __shfl(y1[i], (lane & 48) + 15);
            float inv = 1.0f / li;
            int rowY = b * T_SEQ + q0 + w * 16 + g * 4 + i;
            u16* yr = &Ybuf[(size_t)rowY * 192 + h * 21];
            yr[k15] = f2bf(y0[i] * inv);
            if (k15 < 5) yr[16 + k15] = f2bf(y1[i] * inv);
        }
    } else { // bf16 partials (denominator at d=31)
#pragma unroll
        for (int i = 0; i < 4; i++) {
            size_t pb = (size_t)ci * PART_SLOT +
                        (((size_t)bh << 11) + q0 + w * 16 + g * 4 + i) * 32;
            Part[pb + k15] = f2bf(y0[i]);
            Part[pb + 16 + k15] = f2bf(y1[i]);
        }
    }
}

// combine nc partial slots for rows t >= 512, normalize, write Ybuf. nc = (t>>9)+1.
__global__ __launch_bounds__(256) void attn_reduce(const u16* __restrict__ Part, u16* __restrict__ Ybuf) {
    int gid = blockIdx.x * 256 + threadIdx.x; // 36 * 1536 * 32
    int d = gid & 31;
    int rest = gid >> 5;
    int t = 512 + (rest % 1536);
    int bh = rest / 1536;
    int b = bh / N_HEADS, h = bh - b * N_HEADS;
    int nc = (t >> 9) + 1;
    size_t base = (((size_t)bh << 11) + t) * 32;
    float l = 0.f, v = 0.f;
    for (int ci = 0; ci < nc; ci++) {
        l += bf2f(Part[(size_t)ci * PART_SLOT + base + 31]);
        if (d < 21) v += bf2f(Part[(size_t)ci * PART_SLOT + base + d]);
    }
    if (d < 21) Ybuf[(size_t)(b * T_SEQ + t) * 192 + h * 21 + d] = f2bf(v / l);
}

// ---------------- launch ----------------

extern "C" void kernel_launch(void* const* d_in, const int* in_sizes, int n_in,
                              void* d_out, int out_size, void* d_ws, size_t ws_size,
                              hipStream_t stream) {
    const float* x  = (const float*)d_in[0];
    const float* Wq = (const float*)d_in[1];
    const float* Wk = (const float*)d_in[2];
    const float* Wv = (const float*)d_in[3];
    const float* Wo = (const float*)d_in[4];
    float* out = (float*)d_out;

    char* p = (char*)d_ws;
    auto alloc = [&](size_t bytes) { char* r = p; p += (bytes + 255) & ~(size_t)255; return r; };
    u16*   QpKp   = (u16*)alloc((size_t)ROWS * CDIM * 2);   // Qp | Kp
    u16*   qkv    = (u16*)alloc((size_t)ROWS * CDIM * 2);
    u16*   WcT    = (u16*)alloc((size_t)576 * 576 * 2);
    u16*   WoSubT = (u16*)alloc((size_t)576 * 192 * 2);
    float* cosT   = (float*)alloc((size_t)T_SEQ * 21 * 4);
    float* sinT   = (float*)alloc((size_t)T_SEQ * 21 * 4);
    u16*   Vp     = (u16*)alloc((size_t)NBH * 32 * T_SEQ * 2);
    u16*   Ybuf   = (u16*)alloc((size_t)ROWS * 192 * 2);
    u16*   Part   = (u16*)alloc((size_t)4 * PART_SLOT * 2);

    u16* Qp = QpKp;
    u16* Kp = QpKp + (size_t)NBH * T_SEQ * 32;

    prep_wt<<<dim3((576 * 576 + 255) / 256), dim3(256), 0, stream>>>(Wq, Wk, Wv, Wo, WcT, WoSubT, cosT, sinT);

    // QKV projection: [8192,576(f32)] x [576,567(->576)] — XCD-aligned 1-D grid (64 m x 9 n)
    gemm_mfma<1, 0><<<dim3(64 * 9), dim3(256), 0, stream>>>((const void*)x, WcT, (void*)qkv, 576, 576, 576, 576);

    // merged rope + repack (vectorized loads; Q/K roped rows, V d-major transpose)
    repack_qkv<<<dim3(T_SEQ / 64, NBH), dim3(256), 0, stream>>>(qkv, cosT, sinT, Qp, Kp, Vp);

    // balanced split-K MFMA flash attention (128 q/block, 8 waves, 256-key units) + combine
    attn_mfma<<<dim3(40, NBH), dim3(512), 0, stream>>>(Qp, Kp, Vp, Ybuf, Part);
    attn_reduce<<<dim3(NBH * 1536 * 32 / 256), dim3(256), 0, stream>>>(Part, Ybuf);

    // output GEMM: [8192,192] x [192,576] — XCD-aligned 1-D grid (64 m x 9 n)
    gemm_mfma<0, 1><<<dim3(64 * 9), dim3(256), 0, stream>>>((const void*)Ybuf, WoSubT, (void*)out, 192, 192, 192, 576);
}

// Round 16
// 77.880 us; speedup vs baseline: 1.1675x; 1.1675x over previous
//
#include <hip/hip_runtime.h>
#include <hip/hip_bf16.h>

typedef unsigned short u16;
typedef unsigned int u32;
typedef __attribute__((ext_vector_type(8))) short bf16x8;
typedef __attribute__((ext_vector_type(4))) float f32x4;
typedef __attribute__((ext_vector_type(4))) int i32x4;

#define N_HEADS 9
#define T_SEQ 2048
#define BATCH 4
#define CDIM 576
#define ROWS (BATCH * T_SEQ) /* 8192 */
#define NBH (BATCH * N_HEADS) /* 36 */
#define PART_SLOT ((size_t)NBH * T_SEQ * 32) /* u16 elements per partial slot */

__device__ __forceinline__ u16 f2bf(float f) {
    u32 u = __float_as_uint(f);
    u32 r = u + 0x7FFFu + ((u >> 16) & 1u);
    return (u16)(r >> 16);
}
__device__ __forceinline__ float bf2f(u16 u) { return __uint_as_float(((u32)u) << 16); }
__device__ __forceinline__ u32 cvt_pk_bf16(float lo, float hi) {
    u32 r;
    asm("v_cvt_pk_bf16_f32 %0, %1, %2" : "=v"(r) : "v"(lo), "v"(hi));
    return r;
}
__device__ __forceinline__ float exp2_raw(float x) {
    float r;
    asm("v_exp_f32 %0, %1" : "=v"(r) : "v"(x));
    return r;
}

// ---------------- merged prep: weights + trig tables ----------------
__global__ __launch_bounds__(256) void prep_wt(const float* __restrict__ Wq, const float* __restrict__ Wk,
                                               const float* __restrict__ Wv, const float* __restrict__ Wo,
                                               u16* __restrict__ WcT, u16* __restrict__ WoSubT,
                                               float* __restrict__ cosT, float* __restrict__ sinT) {
    int idx = blockIdx.x * 256 + threadIdx.x;
    if (idx < 576 * 576) {
        int n = idx / 576, k = idx - n * 576;
        float v;
        if (n < 189)      v = Wq[(size_t)k * 576 + (n / 21) * 64 + (n % 21)];
        else if (n < 378) v = Wk[(size_t)k * 189 + (n - 189)];
        else if (n < 567) v = Wv[(size_t)k * 189 + (n - 378)];
        else              v = 0.f;
        WcT[(size_t)n * 576 + k] = f2bf(v);
    }
    if (idx < 576 * 192) {
        int n = idx / 192, k = idx - n * 192;
        float v = 0.f;
        if (k < 189) v = Wo[(size_t)((k / 21) * 64 + (k % 21)) * 576 + n];
        WoSubT[(size_t)n * 192 + k] = f2bf(v);
    }
    if (idx < T_SEQ * 21) {
        int t = idx / 21, d = idx - t * 21;
        int i = (d < 11) ? d : d - 11;
        float e = (2.0f * (float)i) / 21.0f;
        float invf = exp2f(-e * 13.287712379549449f); // 10000^-e
        float ang = (float)t * invf;
        cosT[idx] = cosf(ang);
        sinT[idx] = sinf(ang);
    }
}

// ---------------- bf16 MFMA GEMM (round-14 form): C[M,N] = A[M,K] * BT[N,K]^T ----------------
// 128x64 tile, 4 waves, BK=32. 1-D grid, m = bx&63, n = bx>>6: blocks sharing an A panel land
// on the same XCD L2 -> A fetched from HBM once. AF32: A f32, converted in staging.

template <int AF32, int OUTF32>
__global__ __launch_bounds__(256) void gemm_mfma(const void* __restrict__ Av, const u16* __restrict__ BT,
                                                 void* __restrict__ Cout, int K, int lda, int ldbt, int ldc) {
    __shared__ u16 As[128][32];
    __shared__ u16 Bs[64][32];
    const int tid = threadIdx.x;
    const int lane = tid & 63, w = tid >> 6;
    const int m0 = (blockIdx.x & 63) * 128, n0 = (blockIdx.x >> 6) * 64;
    const int k15 = lane & 15, g = lane >> 4;

    const int arow = tid >> 1;          // 0..127
    const int ac0 = (tid & 1) * 2;      // chunks ac0, ac0+1
    const int brow = tid >> 2, bc = tid & 3;

    f32x4 zero = {0.f, 0.f, 0.f, 0.f};
    f32x4 acc[2][4];
#pragma unroll
    for (int hf = 0; hf < 2; hf++)
#pragma unroll
        for (int n = 0; n < 4; n++) acc[hf][n] = zero;

    const float* Af = (const float*)Av;
    const u16*   Ab = (const u16*)Av;

    float4 af0, af1, af2, af3;
    i32x4 av0, av1;
    if (AF32) {
        const float* ap = &Af[(size_t)(m0 + arow) * lda + ac0 * 8];
        af0 = *(const float4*)&ap[0];
        af1 = *(const float4*)&ap[4];
        af2 = *(const float4*)&ap[8];
        af3 = *(const float4*)&ap[12];
    } else {
        av0 = *(const i32x4*)&Ab[(size_t)(m0 + arow) * lda + ac0 * 8];
        av1 = *(const i32x4*)&Ab[(size_t)(m0 + arow) * lda + (ac0 + 1) * 8];
    }
    i32x4 bv = *(const i32x4*)&BT[(size_t)(n0 + brow) * ldbt + bc * 8];

    for (int k0 = 0; k0 < K; k0 += 32) {
        __syncthreads();
        if (AF32) {
            i32x4 w0, w1;
            w0[0] = (int)cvt_pk_bf16(af0.x, af0.y); w0[1] = (int)cvt_pk_bf16(af0.z, af0.w);
            w0[2] = (int)cvt_pk_bf16(af1.x, af1.y); w0[3] = (int)cvt_pk_bf16(af1.z, af1.w);
            w1[0] = (int)cvt_pk_bf16(af2.x, af2.y); w1[1] = (int)cvt_pk_bf16(af2.z, af2.w);
            w1[2] = (int)cvt_pk_bf16(af3.x, af3.y); w1[3] = (int)cvt_pk_bf16(af3.z, af3.w);
            *(i32x4*)&As[arow][(ac0 ^ (arow & 3)) * 8] = w0;
            *(i32x4*)&As[arow][((ac0 + 1) ^ (arow & 3)) * 8] = w1;
        } else {
            *(i32x4*)&As[arow][(ac0 ^ (arow & 3)) * 8] = av0;
            *(i32x4*)&As[arow][((ac0 + 1) ^ (arow & 3)) * 8] = av1;
        }
        *(i32x4*)&Bs[brow][(bc ^ (brow & 3)) * 8] = bv;
        __syncthreads();
        int k1 = k0 + 32;
        if (k1 < K) {
            if (AF32) {
                const float* ap = &Af[(size_t)(m0 + arow) * lda + k1 + ac0 * 8];
                af0 = *(const float4*)&ap[0];
                af1 = *(const float4*)&ap[4];
                af2 = *(const float4*)&ap[8];
                af3 = *(const float4*)&ap[12];
            } else {
                av0 = *(const i32x4*)&Ab[(size_t)(m0 + arow) * lda + k1 + ac0 * 8];
                av1 = *(const i32x4*)&Ab[(size_t)(m0 + arow) * lda + k1 + (ac0 + 1) * 8];
            }
            bv = *(const i32x4*)&BT[(size_t)(n0 + brow) * ldbt + k1 + bc * 8];
        }
        const int ar0 = w * 32 + k15;
        bf16x8 a0 = *(const bf16x8*)&As[ar0][(g ^ (ar0 & 3)) * 8];
        bf16x8 a1 = *(const bf16x8*)&As[ar0 + 16][(g ^ (ar0 & 3)) * 8];
#pragma unroll
        for (int n = 0; n < 4; n++) {
            int br = n * 16 + k15;
            bf16x8 b = *(const bf16x8*)&Bs[br][(g ^ (br & 3)) * 8];
            acc[0][n] = __builtin_amdgcn_mfma_f32_16x16x32_bf16(a0, b, acc[0][n], 0, 0, 0);
            acc[1][n] = __builtin_amdgcn_mfma_f32_16x16x32_bf16(a1, b, acc[1][n], 0, 0, 0);
        }
    }
#pragma unroll
    for (int hf = 0; hf < 2; hf++)
#pragma unroll
        for (int n = 0; n < 4; n++)
#pragma unroll
            for (int i = 0; i < 4; i++) {
                int row = m0 + w * 32 + hf * 16 + g * 4 + i;
                int col = n0 + n * 16 + k15;
                float v = acc[hf][n][i];
                if (OUTF32) ((float*)Cout)[(size_t)row * ldc + col] = v;
                else        ((u16*)Cout)[(size_t)row * ldc + col] = f2bf(v);
            }
}

// ---------------- merged repack: rope Q/K + V transpose, vectorized loads ----------------

__global__ __launch_bounds__(256) void repack_qkv(const u16* __restrict__ qkv,
                                                  const float* __restrict__ cosT,
                                                  const float* __restrict__ sinT,
                                                  u16* __restrict__ Qp, u16* __restrict__ Kp,
                                                  u16* __restrict__ Vp) {
    __shared__ u16 Qs[64][40];
    __shared__ u16 Ksh[64][40];
    __shared__ u16 Vsh[64][40];
    const int tid = threadIdx.x;
    const int bh = blockIdx.y;
    const int b = bh / N_HEADS, h = bh - b * N_HEADS;
    const int t0 = blockIdx.x * 64;

    const int qa = (h * 21) & ~7,        qoff = h * 21 - qa;
    const int ka = (189 + h * 21) & ~7,  koff = 189 + h * 21 - ka;
    const int va = (378 + h * 21) & ~7,  voff = 378 + h * 21 - va;

#pragma unroll
    for (int it = 0; it < 3; ++it) {
        int idx = tid + it * 256;  // 0..767
        int row = idx / 12;
        int r12 = idx - row * 12;
        int stream = r12 >> 2, chunk = r12 & 3;
        int off = (stream == 0) ? qa : (stream == 1) ? ka : va;
        const u16* src = qkv + (size_t)(b * T_SEQ + t0 + row) * CDIM + off + chunk * 8;
        i32x4 v = *(const i32x4*)src;
        u16* dst = (stream == 0) ? &Qs[row][0] : (stream == 1) ? &Ksh[row][0] : &Vsh[row][0];
        *(i32x4*)&dst[chunk * 8] = v;
    }
    __syncthreads();

    const int r = tid >> 2, c = tid & 3;
    const int t = t0 + r;
    const float* cr = cosT + t * 21;
    const float* sr = sinT + t * 21;
    u32 wq[4] = {0, 0, 0, 0}, wk[4] = {0, 0, 0, 0};
    const float sc = 0.18033688011112042f; // 0.125 * log2(e)
#pragma unroll
    for (int j = 0; j < 8; j++) {
        int d = c * 8 + j;
        float vq = 0.f, vk = 0.f;
        if (d < 21) {
            int pd = (d < 11) ? d + 10 : d - 11;
            float cc = cr[d], ss = sr[d];
            float qv = bf2f(Qs[r][qoff + d]),  qp = bf2f(Qs[r][qoff + pd]);
            float kv = bf2f(Ksh[r][koff + d]), kp = bf2f(Ksh[r][koff + pd]);
            float rq = (d < 11) ? -qp : qp;
            float rk = (d < 11) ? -kp : kp;
            vq = (qv * cc + rq * ss) * sc;
            vk = kv * cc + rk * ss;
        }
        wq[j >> 1] |= (u32)f2bf(vq) << ((j & 1) * 16);
        wk[j >> 1] |= (u32)f2bf(vk) << ((j & 1) * 16);
    }
    size_t obase = ((size_t)bh * T_SEQ + t) * 32 + c * 8;
    i32x4 q4; q4[0] = (int)wq[0]; q4[1] = (int)wq[1]; q4[2] = (int)wq[2]; q4[3] = (int)wq[3];
    i32x4 k4; k4[0] = (int)wk[0]; k4[1] = (int)wk[1]; k4[2] = (int)wk[2]; k4[3] = (int)wk[3];
    *(i32x4*)&Qp[obase] = q4;
    *(i32x4*)&Kp[obase] = k4;

    const int dv = tid >> 3, tc = tid & 7;
    u32 wv[4];
#pragma unroll
    for (int j = 0; j < 4; j++) {
        u16 lo, hi;
        if (dv < 21)      { lo = Vsh[tc * 8 + j * 2][voff + dv]; hi = Vsh[tc * 8 + j * 2 + 1][voff + dv]; }
        else if (dv == 31){ lo = 0x3F80; hi = 0x3F80; }
        else              { lo = 0; hi = 0; }
        wv[j] = (u32)lo | ((u32)hi << 16);
    }
    i32x4 v4; v4[0] = (int)wv[0]; v4[1] = (int)wv[1]; v4[2] = (int)wv[2]; v4[3] = (int)wv[3];
    *(i32x4*)&Vp[((size_t)bh * 32 + dv) * T_SEQ + t0 + tc * 8] = v4;
}

// ---------------- split-K MFMA flash attention: 128 q/block, 8 waves, 128-key units ----------------
// Round-14 structure + (a) 1-barrier double-buffered K/V staging, (b) s_setprio around MFMA.
// Barrier at iteration top guarantees: prior iter's ds_writes to buf[cur] visible AND prior
// compute of buf[cur^1] done. Wave enters compute right after its own writes (no write-drain wait).

__global__ __launch_bounds__(512) void attn_mfma(const u16* __restrict__ Qp,
                                                 const u16* __restrict__ Kp,
                                                 const u16* __restrict__ Vp,
                                                 u16* __restrict__ Ybuf,
                                                 u16* __restrict__ Part) {
    __shared__ u16 Ks[2][128][40];    // double-buffered, 80B rows
    __shared__ u16 Vt[2][32][136];    // double-buffered, 272B rows
    __shared__ u16 Pt[2][8][16][72];  // [sub][wave][q][key]
    const int tid = threadIdx.x;
    const int lane = tid & 63, w = tid >> 6;   // w 0..7
    const int bh = blockIdx.y;
    const int b = bh / N_HEADS, h = bh - b * N_HEADS;
    const int k15 = lane & 15, g = lane >> 4;

    // bx -> (qt2, ci), heavy q-tiles first. nc(qt2) = (qt2>>2)+1, sum = 40.
    int qt2 = 15, ci = blockIdx.x;
    for (int q = 15; q >= 0; --q) {
        int n = (q >> 2) + 1;
        if (ci < n) { qt2 = q; break; }
        ci -= n;
    }
    const int q0 = qt2 * 128;
    const int n128 = qt2 + 1;            // 128-key units covering keys 0..q0+127
    const int nc = (qt2 >> 2) + 1;
    const int u_begin = (ci * n128) / nc;
    const int u_end = ((ci + 1) * n128) / nc;

    // staging: threads 0..255 stage K (128x32), 256..511 stage V (32x128); 2x16B each
    const bool isK = (tid < 256);
    const int krow = (tid & 255) >> 2, kc = tid & 3;       // K: rows krow, krow+64
    const int vrow = (tid & 255) >> 3, vc = tid & 7;       // V: chunks vc, vc+8
    const u16* Kg = Kp + (size_t)bh * 65536 + krow * 32 + kc * 8;
    const u16* Vg = Vp + (size_t)bh * 65536 + vrow * 2048 + vc * 8;

    // Q B-fragment held in regs: B[n=q][k=d]
    bf16x8 qf = *(const bf16x8*)&Qp[(((size_t)bh << 11) + q0 + w * 16 + k15) * 32 + g * 8];

    f32x4 y0 = {0.f, 0.f, 0.f, 0.f}, y1 = {0.f, 0.f, 0.f, 0.f};
    const int qloc = (w & 3) * 16 + k15;       // q position within its 64-aligned block
    const int kd = 2 * qt2 + (w >> 2);         // wave's diagonal 64-key tile index

    // prologue: load unit u_begin -> regs -> buf0 (no barrier needed: disjoint writes)
    u32 koff = (u32)u_begin * 4096u;           // K: u16 elems per unit (128*32)
    u32 voffu = (u32)u_begin * 128u;           // V: u16 elems per unit per row
    i32x4 r0, r1;
    if (isK) { r0 = *(const i32x4*)&Kg[koff];   r1 = *(const i32x4*)&Kg[koff + 2048]; }
    else     { r0 = *(const i32x4*)&Vg[voffu];  r1 = *(const i32x4*)&Vg[voffu + 64]; }
    if (isK) {
        *(i32x4*)&Ks[0][krow][kc * 8] = r0;
        *(i32x4*)&Ks[0][krow + 64][kc * 8] = r1;
    } else {
        *(i32x4*)&Vt[0][vrow][vc * 8] = r0;
        *(i32x4*)&Vt[0][vrow][vc * 8 + 64] = r1;
    }
    if (u_begin + 1 < u_end) {                 // preload next unit into regs
        koff += 4096u; voffu += 128u;
        if (isK) { r0 = *(const i32x4*)&Kg[koff];   r1 = *(const i32x4*)&Kg[koff + 2048]; }
        else     { r0 = *(const i32x4*)&Vg[voffu];  r1 = *(const i32x4*)&Vg[voffu + 64]; }
    }

    int cur = 0;
    for (int u = u_begin; u < u_end; ++u) {
        __syncthreads();   // buf[cur] writes visible; buf[cur^1] compute (prev iter) done
        if (u + 1 < u_end) {
            if (isK) {
                *(i32x4*)&Ks[cur ^ 1][krow][kc * 8] = r0;
                *(i32x4*)&Ks[cur ^ 1][krow + 64][kc * 8] = r1;
            } else {
                *(i32x4*)&Vt[cur ^ 1][vrow][vc * 8] = r0;
                *(i32x4*)&Vt[cur ^ 1][vrow][vc * 8 + 64] = r1;
            }
            if (u + 2 < u_end) {               // prefetch unit u+2 (overlaps compute)
                koff += 4096u; voffu += 128u;
                if (isK) { r0 = *(const i32x4*)&Kg[koff];   r1 = *(const i32x4*)&Kg[koff + 2048]; }
                else     { r0 = *(const i32x4*)&Vg[voffu];  r1 = *(const i32x4*)&Vg[voffu + 64]; }
            }
        }

        const int kt0 = u * 2;
        const bool do0 = (kt0 <= kd);
        const bool do1 = (kt0 + 1 <= kd);

        if (do0) {
            f32x4 s0[4], s1[4];
            __builtin_amdgcn_s_setprio(1);
#pragma unroll
            for (int f = 0; f < 4; f++) {
                bf16x8 kf = *(const bf16x8*)&Ks[cur][f * 16 + k15][g * 8];
                f32x4 z = {0.f, 0.f, 0.f, 0.f};
                s0[f] = __builtin_amdgcn_mfma_f32_16x16x32_bf16(kf, qf, z, 0, 0, 0);
            }
            if (do1) {
#pragma unroll
                for (int f = 0; f < 4; f++) {
                    bf16x8 kf = *(const bf16x8*)&Ks[cur][64 + f * 16 + k15][g * 8];
                    f32x4 z = {0.f, 0.f, 0.f, 0.f};
                    s1[f] = __builtin_amdgcn_mfma_f32_16x16x32_bf16(kf, qf, z, 0, 0, 0);
                }
            }
            __builtin_amdgcn_s_setprio(0);

            if (kt0 == kd) {
#pragma unroll
                for (int f = 0; f < 4; f++)
#pragma unroll
                    for (int i = 0; i < 4; i++)
                        if (f * 16 + g * 4 + i > qloc) s0[f][i] = -16384.f;
            }
            if (do1 && kt0 + 1 == kd) {
#pragma unroll
                for (int f = 0; f < 4; f++)
#pragma unroll
                    for (int i = 0; i < 4; i++)
                        if (f * 16 + g * 4 + i > qloc) s1[f][i] = -16384.f;
            }

#pragma unroll
            for (int f = 0; f < 4; f++) {
                u32 lo = cvt_pk_bf16(exp2_raw(s0[f][0]), exp2_raw(s0[f][1]));
                u32 hi = cvt_pk_bf16(exp2_raw(s0[f][2]), exp2_raw(s0[f][3]));
                uint2 pk; pk.x = lo; pk.y = hi;
                *(uint2*)&Pt[0][w][k15][f * 16 + g * 4] = pk;
            }
            if (do1) {
#pragma unroll
                for (int f = 0; f < 4; f++) {
                    u32 lo = cvt_pk_bf16(exp2_raw(s1[f][0]), exp2_raw(s1[f][1]));
                    u32 hi = cvt_pk_bf16(exp2_raw(s1[f][2]), exp2_raw(s1[f][3]));
                    uint2 pk; pk.x = lo; pk.y = hi;
                    *(uint2*)&Pt[1][w][k15][f * 16 + g * 4] = pk;
                }
            }
            asm volatile("" ::: "memory"); // Pt writes ordered before reads (wave-local)

            __builtin_amdgcn_s_setprio(1);
#pragma unroll
            for (int kh = 0; kh < 2; kh++) {
                bf16x8 pa = *(const bf16x8*)&Pt[0][w][k15][kh * 32 + g * 8];
                bf16x8 v0 = *(const bf16x8*)&Vt[cur][k15][kh * 32 + g * 8];
                bf16x8 v1 = *(const bf16x8*)&Vt[cur][16 + k15][kh * 32 + g * 8];
                y0 = __builtin_amdgcn_mfma_f32_16x16x32_bf16(pa, v0, y0, 0, 0, 0);
                y1 = __builtin_amdgcn_mfma_f32_16x16x32_bf16(pa, v1, y1, 0, 0, 0);
            }
            if (do1) {
#pragma unroll
                for (int kh = 0; kh < 2; kh++) {
                    bf16x8 pa = *(const bf16x8*)&Pt[1][w][k15][kh * 32 + g * 8];
                    bf16x8 v0 = *(const bf16x8*)&Vt[cur][k15][64 + kh * 32 + g * 8];
                    bf16x8 v1 = *(const bf16x8*)&Vt[cur][16 + k15][64 + kh * 32 + g * 8];
                    y0 = __builtin_amdgcn_mfma_f32_16x16x32_bf16(pa, v0, y0, 0, 0, 0);
                    y1 = __builtin_amdgcn_mfma_f32_16x16x32_bf16(pa, v1, y1, 0, 0, 0);
                }
            }
            __builtin_amdgcn_s_setprio(0);
            asm volatile("" ::: "memory"); // Pt reads done before next unit's writes
        }
        cur ^= 1;
    }

    if (nc == 1) { // qt2 < 4: single chunk, normalize by l (= y1 col 15 ones-column), write
#pragma unroll
        for (int i = 0; i < 4; i++) {
            float li = __shfl(y1[i], (lane & 48) + 15);
            float inv = 1.0f / li;
            int rowY = b * T_SEQ + q0 + w * 16 + g * 4 + i;
            u16* yr = &Ybuf[(size_t)rowY * 192 + h * 21];
            yr[k15] = f2bf(y0[i] * inv);
            if (k15 < 5) yr[16 + k15] = f2bf(y1[i] * inv);
        }
    } else { // bf16 partials (denominator at d=31)
#pragma unroll
        for (int i = 0; i < 4; i++) {
            size_t pb = (size_t)ci * PART_SLOT +
                        (((size_t)bh << 11) + q0 + w * 16 + g * 4 + i) * 32;
            Part[pb + k15] = f2bf(y0[i]);
            Part[pb + 16 + k15] = f2bf(y1[i]);
        }
    }
}

// combine nc partial slots for rows t >= 512, normalize, write Ybuf. nc = (t>>9)+1.
__global__ __launch_bounds__(256) void attn_reduce(const u16* __restrict__ Part, u16* __restrict__ Ybuf) {
    int gid = blockIdx.x * 256 + threadIdx.x; // 36 * 1536 * 32
    int d = gid & 31;
    int rest = gid >> 5;
    int t = 512 + (rest % 1536);
    int bh = rest / 1536;
    int b = bh / N_HEADS, h = bh - b * N_HEADS;
    int nc = (t >> 9) + 1;
    size_t base = (((size_t)bh << 11) + t) * 32;
    float l = 0.f, v = 0.f;
    for (int ci = 0; ci < nc; ci++) {
        l += bf2f(Part[(size_t)ci * PART_SLOT + base + 31]);
        if (d < 21) v += bf2f(Part[(size_t)ci * PART_SLOT + base + d]);
    }
    if (d < 21) Ybuf[(size_t)(b * T_SEQ + t) * 192 + h * 21 + d] = f2bf(v / l);
}

// ---------------- launch ----------------

extern "C" void kernel_launch(void* const* d_in, const int* in_sizes, int n_in,
                              void* d_out, int out_size, void* d_ws, size_t ws_size,
                              hipStream_t stream) {
    const float* x  = (const float*)d_in[0];
    const float* Wq = (const float*)d_in[1];
    const float* Wk = (const float*)d_in[2];
    const float* Wv = (const float*)d_in[3];
    const float* Wo = (const float*)d_in[4];
    float* out = (float*)d_out;

    char* p = (char*)d_ws;
    auto alloc = [&](size_t bytes) { char* r = p; p += (bytes + 255) & ~(size_t)255; return r; };
    u16*   QpKp   = (u16*)alloc((size_t)ROWS * CDIM * 2);   // Qp | Kp
    u16*   qkv    = (u16*)alloc((size_t)ROWS * CDIM * 2);
    u16*   WcT    = (u16*)alloc((size_t)576 * 576 * 2);
    u16*   WoSubT = (u16*)alloc((size_t)576 * 192 * 2);
    float* cosT   = (float*)alloc((size_t)T_SEQ * 21 * 4);
    float* sinT   = (float*)alloc((size_t)T_SEQ * 21 * 4);
    u16*   Vp     = (u16*)alloc((size_t)NBH * 32 * T_SEQ * 2);
    u16*   Ybuf   = (u16*)alloc((size_t)ROWS * 192 * 2);
    u16*   Part   = (u16*)alloc((size_t)4 * PART_SLOT * 2);

    u16* Qp = QpKp;
    u16* Kp = QpKp + (size_t)NBH * T_SEQ * 32;

    prep_wt<<<dim3((576 * 576 + 255) / 256), dim3(256), 0, stream>>>(Wq, Wk, Wv, Wo, WcT, WoSubT, cosT, sinT);

    // QKV projection: [8192,576(f32)] x [576,567(->576)] — XCD-aligned 1-D grid (64 m x 9 n)
    gemm_mfma<1, 0><<<dim3(64 * 9), dim3(256), 0, stream>>>((const void*)x, WcT, (void*)qkv, 576, 576, 576, 576);

    // merged rope + repack (vectorized loads; Q/K roped rows, V d-major transpose)
    repack_qkv<<<dim3(T_SEQ / 64, NBH), dim3(256), 0, stream>>>(qkv, cosT, sinT, Qp, Kp, Vp);

    // balanced split-K MFMA flash attention (128 q/block, 8 waves, dbuf staging) + combine
    attn_mfma<<<dim3(40, NBH), dim3(512), 0, stream>>>(Qp, Kp, Vp, Ybuf, Part);
    attn_reduce<<<dim3(NBH * 1536 * 32 / 256), dim3(256), 0, stream>>>(Part, Ybuf);

    // output GEMM: [8192,192] x [192,576] — XCD-aligned 1-D grid (64 m x 9 n)
    gemm_mfma<0, 1><<<dim3(64 * 9), dim3(256), 0, stream>>>((const void*)Ybuf, WoSubT, (void*)out, 192, 192, 192, 576);
}